// Round 11
// baseline (116439.783 us; speedup 1.0000x reference)
//
#include <hip/hip_runtime.h>
#include <math.h>

typedef _Float16 f16;
typedef __attribute__((ext_vector_type(8))) _Float16 f16x8;
typedef __attribute__((ext_vector_type(4))) float f32x4;

#define Bsz 256
#define Tsz 196
#define Fsz 263
#define TFs (Tsz*Fsz)   // 51548
#define SX  1312        // X row stride (288 frame-pad + 1024 h)
#define KCH 41
#define LOSC 2048.0f
#define LOINV 0.00048828125f

// ---------------- ws layout (BYTE offsets) ----------------
#define OFF_WPK    0u            // packed W [41][64][2][64col][32k] f16 = 21495808 B
#define OFF_CST    21495808u     // c state f32 [256][1024] = 1048576
#define OFF_CGP    22544384u     // constG permuted f32 [256][4096] = 4194304
#define OFF_PROJ   26738688u     // (scratch only now) 2621440
#define OFF_L2PH   29360128u     // lin2 pack hi [32][5][2048] f16 = 655360
#define OFF_L2PL   30015488u
#define OFF_XHI0   30670848u     // 671744 each
#define OFF_XLO0   31342592u
#define OFF_XHI1   32014336u
#define OFF_XLO1   32686080u
#define OFF_WCOMB  33357824u     // scratch 4718592
#define OFF_CGJ    38076416u     // scratch 4194304
#define OFF_WCT    42270720u     // scratch 4718592
#define WS_BYTES   46989312u

__device__ __forceinline__ void glds16(const void* g, void* l) {
    __builtin_amdgcn_global_load_lds(
        (const __attribute__((address_space(1))) void*)g,
        (__attribute__((address_space(3))) void*)l, 16, 0, 0);
}
__device__ __forceinline__ float sigm(float x) { return 1.f / (1.f + expf(-x)); }
__device__ __forceinline__ void split16(float x, f16& hi, f16& lo) {
    hi = (f16)x;
    lo = (f16)((x - (float)hi) * LOSC);
}
#define MFMA16(a,b,c) __builtin_amdgcn_mfma_f32_16x16x32_f16(a,b,c,0,0,0)
#define WAIT_BAR(N) do { \
    asm volatile("s_waitcnt vmcnt(" #N ")" ::: "memory"); \
    __builtin_amdgcn_s_barrier(); \
    __builtin_amdgcn_sched_barrier(0); \
} while (0)

// ---------------- precompute kernels ----------------
__global__ __launch_bounds__(256) void tpose(const float* __restrict__ src,
                                             float* __restrict__ dst, int M, int N) {
    __shared__ float tile[32][33];
    int bx = blockIdx.x, by = blockIdx.y;
    int tx = threadIdx.x & 31, ty = threadIdx.x >> 5;
#pragma unroll
    for (int i = 0; i < 4; ++i) {
        int row = by*32 + ty*4 + i, col = bx*32 + tx;
        tile[ty*4+i][tx] = (row < M && col < N) ? src[(size_t)row*N + col] : 0.f;
    }
    __syncthreads();
#pragma unroll
    for (int i = 0; i < 4; ++i) {
        int row = bx*32 + ty*4 + i, col = by*32 + tx;
        if (row < N && col < M) dst[(size_t)row*M + col] = tile[tx][ty*4+i];
    }
}

__global__ __launch_bounds__(256) void biasg_k(const float* __restrict__ bih,
                                               const float* __restrict__ bhh,
                                               const float* __restrict__ l1b,
                                               const float* __restrict__ wih,
                                               float* __restrict__ bg) {
    int j = blockIdx.x*4 + (threadIdx.x >> 6);
    int l = threadIdx.x & 63;
    const float* wr = wih + (size_t)j*1024 + l*8;
    const float* lb = l1b + l*8;
    float s = 0.f;
#pragma unroll
    for (int e = 0; e < 8; ++e) s += lb[e] * wr[e];
#pragma unroll
    for (int off = 32; off; off >>= 1) s += __shfl_down(s, off, 64);
    if (l == 0) bg[j] = bih[j] + bhh[j] + s;
}

__global__ __launch_bounds__(256) void nn_gemm(const float* __restrict__ A,
                                               const float* __restrict__ B,
                                               const float* __restrict__ bias,
                                               float* __restrict__ C,
                                               int M, int MA, int N, int K) {
    __shared__ float As[32][33];
    __shared__ float Bs[32][64];
    int tid = threadIdx.x;
    int r0 = blockIdx.y*32, c0 = blockIdx.x*64;
    int tr = tid >> 4, tc = tid & 15;
    float acc[2][4] = {};
    for (int k0 = 0; k0 < K; k0 += 32) {
        int m = tid >> 3, kb = (tid & 7)*4;
        int row = r0 + m;
#pragma unroll
        for (int i = 0; i < 4; ++i)
            As[m][kb+i] = (row < MA) ? A[(size_t)row*K + k0 + kb + i] : 0.f;
#pragma unroll
        for (int i = 0; i < 8; ++i) {
            int fi = i*256 + tid, kk = fi >> 6, cc = fi & 63;
            Bs[kk][cc] = B[(size_t)(k0+kk)*N + c0 + cc];
        }
        __syncthreads();
#pragma unroll
        for (int k = 0; k < 32; ++k) {
            float a0 = As[2*tr][k], a1 = As[2*tr+1][k];
            float b0 = Bs[k][4*tc], b1 = Bs[k][4*tc+1], b2 = Bs[k][4*tc+2], b3 = Bs[k][4*tc+3];
            acc[0][0]+=a0*b0; acc[0][1]+=a0*b1; acc[0][2]+=a0*b2; acc[0][3]+=a0*b3;
            acc[1][0]+=a1*b0; acc[1][1]+=a1*b1; acc[1][2]+=a1*b2; acc[1][3]+=a1*b3;
        }
        __syncthreads();
    }
#pragma unroll
    for (int i = 0; i < 2; ++i) {
        int row = r0 + 2*tr + i;
        if (row < M)
#pragma unroll
            for (int j = 0; j < 4; ++j) {
                int col = c0 + 4*tc + j;
                C[(size_t)row*N + col] = acc[i][j] + (bias ? bias[col] : 0.f);
            }
    }
}

// pack W: [kc][ct=64][limb=2][col=64][kslot=4][8] f16, chunk = 8KB.
// slot s of col c holds kgroup g = s ^ ((c>>1)&3)  (matches compute-side XOR read)
__global__ __launch_bounds__(256) void pack_w(const float* __restrict__ WcT,
                                              const float* __restrict__ whh,
                                              f16* __restrict__ W) {
    int tid = threadIdx.x;
    int ct = blockIdx.x, kc = blockIdx.y;   // 64, 41
    int c = tid >> 2, s = tid & 3;
    int g = s ^ ((c >> 1) & 3);
    int p = ct*64 + c;
    int j = (p & 3)*1024 + (p >> 2);
#pragma unroll
    for (int limb = 0; limb < 2; ++limb) {
        size_t ob = ((size_t)(kc*64 + ct))*4096 + limb*2048 + c*32 + s*8;
#pragma unroll
        for (int e = 0; e < 8; ++e) {
            int k = kc*32 + g*8 + e;
            float v = (k < 288) ? WcT[(size_t)j*288 + k]
                                : whh[(size_t)j*1024 + (k - 288)];
            f16 hi, lo;
            split16(v, hi, lo);
            W[ob + e] = limb ? lo : hi;
        }
    }
}

// lin2 pack: chunks [kc 0..31][ct 0..4] of 2048 f16 (64 cols x 32 k), per limb
__global__ __launch_bounds__(256) void pack_lin2(const float* __restrict__ l2w,
                                                 f16* __restrict__ Lh,
                                                 f16* __restrict__ Ll) {
    int q = threadIdx.x;
    int ct = blockIdx.x, kc = blockIdx.y;   // ct<5, kc<32
    int k = kc*32 + (((q&3) ^ ((q>>3)&3)) << 3);
    int f = ct*64 + (q>>2);
    size_t ob = ((size_t)(kc*5 + ct)*256 + q)*8;
#pragma unroll
    for (int e = 0; e < 8; ++e) {
        float v = (f < Fsz) ? l2w[(size_t)f*1024 + k + e] : 0.f;
        split16(v, Lh[ob+e], Ll[ob+e]);
    }
}

__global__ __launch_bounds__(256) void permute_cg(const float* __restrict__ cj,
                                                  float* __restrict__ cp) {
    int idx = blockIdx.x*256 + threadIdx.x;
    int b = idx >> 12, p = idx & 4095;
    cp[idx] = cj[(b << 12) + ((p & 3) << 10) + (p >> 2)];
}

__global__ __launch_bounds__(256) void init_k(const float* __restrict__ motions,
                                              f16* __restrict__ Xh0,
                                              f16* __restrict__ Xl0,
                                              float* __restrict__ cSt) {
    int idx = blockIdx.x*256 + threadIdx.x;
    if (idx < 256*SX) {
        int b = idx / SX, k = idx - b*SX;
        float v = (k < Fsz) ? motions[(size_t)b*TFs + k] : 0.f;
        split16(v, Xh0[idx], Xl0[idx]);
    } else if (idx < 256*SX + 262144) {
        cSt[idx - 256*SX] = 0.f;
    }
}

// ---------------- k1: gates GEMM (A direct-to-reg, B glds) + cell update ----------------
// grid (64 ct, 4 rt) = 256 blocks, 256 thr, tile 64x64, waves 2x2 (wave 32x32).
// 6 vmem/chunk/thread (4 A-reg + 2 B-glds). Steady WAIT_BAR(6): A,B both 2-chunk cover.
__global__ __launch_bounds__(256) void k1_gates(
        const f16* __restrict__ Xh, const f16* __restrict__ Xl,
        const f16* __restrict__ Wpk,
        const float* __restrict__ cgp, float* __restrict__ cSt,
        f16* __restrict__ XhN, f16* __restrict__ XlN)
{
    __shared__ __attribute__((aligned(16))) char smem[32768];   // 4 B-bufs x 8KB
    const int tid = threadIdx.x;
    const int ct = blockIdx.x, rt = blockIdx.y;
    const int r0 = rt*64, p0 = ct*64;
    const int l = tid & 63;
    const int wr = (tid >> 7) & 1, wc = (tid >> 6) & 1;

    const f16* bSrc  = Wpk + (size_t)ct*4096 + tid*8;
    const f16* aBaseH = Xh + (size_t)(r0 + wr*32 + (l & 15))*SX + (l >> 4)*8;
    const f16* aBaseL = Xl + (size_t)(r0 + wr*32 + (l & 15))*SX + (l >> 4)*8;

    int offB[2];
#pragma unroll
    for (int C = 0; C < 2; ++C) {
        int colB = wc*32 + C*16 + (l & 15);
        offB[C] = colB*64 + ((((l >> 4) ^ ((colB >> 1) & 3)) & 3)*16);
    }
    f32x4 hh[2][2] = {}, hl[2][2] = {}, lh[2][2] = {};
    f16x8 aH[4][2], aL[4][2];

#define ISSUE_B(c_) do { \
    char* dB = smem + ((c_) & 3)*8192 + tid*16; \
    glds16(bSrc + (size_t)(c_)*262144, dB); \
    glds16(bSrc + (size_t)(c_)*262144 + 2048, dB + 4096); } while(0)
#define ISSUE_A(c_, s_) do { \
    const f16* pH = aBaseH + (c_)*32; const f16* pL = aBaseL + (c_)*32; \
    aH[s_][0] = *(const f16x8*)pH; aH[s_][1] = *(const f16x8*)(pH + 16*SX); \
    aL[s_][0] = *(const f16x8*)pL; aL[s_][1] = *(const f16x8*)(pL + 16*SX); } while(0)
#define COMPUTE(c_, s_) do { \
    const char* Bt = smem + ((c_) & 3)*8192; \
    f16x8 bh0 = *(const f16x8*)(Bt + offB[0]); \
    f16x8 bh1 = *(const f16x8*)(Bt + offB[1]); \
    f16x8 bl0 = *(const f16x8*)(Bt + 4096 + offB[0]); \
    f16x8 bl1 = *(const f16x8*)(Bt + 4096 + offB[1]); \
    hh[0][0] = MFMA16(aH[s_][0], bh0, hh[0][0]); \
    hh[0][1] = MFMA16(aH[s_][0], bh1, hh[0][1]); \
    hh[1][0] = MFMA16(aH[s_][1], bh0, hh[1][0]); \
    hh[1][1] = MFMA16(aH[s_][1], bh1, hh[1][1]); \
    hl[0][0] = MFMA16(aH[s_][0], bl0, hl[0][0]); \
    hl[0][1] = MFMA16(aH[s_][0], bl1, hl[0][1]); \
    hl[1][0] = MFMA16(aH[s_][1], bl0, hl[1][0]); \
    hl[1][1] = MFMA16(aH[s_][1], bl1, hl[1][1]); \
    lh[0][0] = MFMA16(aL[s_][0], bh0, lh[0][0]); \
    lh[0][1] = MFMA16(aL[s_][0], bh1, lh[0][1]); \
    lh[1][0] = MFMA16(aL[s_][1], bh0, lh[1][0]); \
    lh[1][1] = MFMA16(aL[s_][1], bh1, lh[1][1]); } while(0)

    // prologue order: A0, A1, B0, A2, B1  (16 ops)
    ISSUE_A(0, 0);
    __builtin_amdgcn_sched_barrier(0);
    ISSUE_A(1, 1);
    __builtin_amdgcn_sched_barrier(0);
    ISSUE_B(0);
    __builtin_amdgcn_sched_barrier(0);
    ISSUE_A(2, 2);
    __builtin_amdgcn_sched_barrier(0);
    ISSUE_B(1);
    __builtin_amdgcn_sched_barrier(0);

#pragma unroll 1
    for (int c = 0; c < 38; ++c) {
        WAIT_BAR(6);
        ISSUE_A(c+3, (c+3) & 3);
        __builtin_amdgcn_sched_barrier(0);
        ISSUE_B(c+2);
        __builtin_amdgcn_sched_barrier(0);
        COMPUTE(c, c & 3);
    }
    WAIT_BAR(6);
    ISSUE_B(40);
    __builtin_amdgcn_sched_barrier(0);
    COMPUTE(38, 2);
    WAIT_BAR(2); COMPUTE(39, 3);
    WAIT_BAR(0); COMPUTE(40, 0);
    __syncthreads();

    // ---- gates -> LDS (swizzled) ----
    float* gl = (float*)smem;   // 64x64 f32 = 16KB
#pragma unroll
    for (int R = 0; R < 2; ++R)
#pragma unroll
        for (int C = 0; C < 2; ++C) {
            f32x4 d = hh[R][C] + (hl[R][C] + lh[R][C]) * LOINV;
            int col = wc*32 + C*16 + (l & 15);
            int rb = wr*32 + R*16 + ((l >> 4) << 2);
#pragma unroll
            for (int j = 0; j < 4; ++j) {
                int r = rb + j;
                gl[r*64 + (col ^ ((r & 7) << 2))] = d[j];
            }
        }
    __syncthreads();
#pragma unroll
    for (int q = 0; q < 4; ++q) {
        int s = q*256 + tid;
        int m = s >> 4, u = s & 15;
        f32x4 gt = *(const f32x4*)(gl + m*64 + ((u << 2) ^ ((m & 7) << 2)));
        f32x4 cg4 = *(const f32x4*)(cgp + (size_t)(r0 + m)*4096 + p0 + (u << 2));
        float gi = gt.x + cg4.x, gf = gt.y + cg4.y, gg = gt.z + cg4.z, go = gt.w + cg4.w;
        int ug = ct*16 + u;
        int ci = (r0 + m)*1024 + ug;
        float cO = cSt[ci];
        float cN = sigm(gf)*cO + sigm(gi)*tanhf(gg);
        float hN = sigm(go)*tanhf(cN);
        cSt[ci] = cN;
        split16(hN, XhN[(size_t)(r0 + m)*SX + 288 + ug],
                    XlN[(size_t)(r0 + m)*SX + 288 + ug]);
    }
#undef ISSUE_B
#undef ISSUE_A
#undef COMPUTE
}

// ---------------- k3: out-projection full-K + fused frame update ----------------
// grid (5 ct, 4 rt) = 20 blocks, tile 64x64, K=1024 (32 chunks). Epilogue writes
// out[:,t,:] and the frame part of X-next (f16 limbs), pads zeroed.
__global__ __launch_bounds__(256) void k3_proj(
        const f16* __restrict__ Xh, const f16* __restrict__ Xl,  // next-buf (holds h_t)
        const f16* __restrict__ Lh, const f16* __restrict__ Ll,
        const float* __restrict__ fprev, const float* __restrict__ l2b,
        float* __restrict__ outT,
        f16* __restrict__ XhN, f16* __restrict__ XlN)
{
    __shared__ __attribute__((aligned(16))) char smem[65536];   // 4 bufs x 16KB
    const int tid = threadIdx.x;
    const int ct = blockIdx.x, rt = blockIdx.y;
    const int r0 = rt*64;
    const int l = tid & 63;
    const int wr = (tid >> 7) & 1, wc = (tid >> 6) & 1;

    const int aswz = (((tid&3) ^ ((tid>>3)&3)) << 3);
    const f16* aSrcH = Xh + (size_t)(r0 + (tid>>2))*SX + 288 + aswz;
    const f16* aSrcL = Xl + (size_t)(r0 + (tid>>2))*SX + 288 + aswz;
    const f16* bSrcH = Lh + (size_t)ct*2048 + tid*8;
    const f16* bSrcL = Ll + (size_t)ct*2048 + tid*8;

    int offA[2], offB[2];
#pragma unroll
    for (int R = 0; R < 2; ++R) {
        int g = l >> 4;
        int row = wr*32 + R*16 + (l & 15);
        offA[R] = row*64 + ((g ^ ((row>>1)&3)) & 3)*16;
        int col = wc*32 + R*16 + (l & 15);
        offB[R] = col*64 + ((g ^ ((col>>1)&3)) & 3)*16;
    }
    f32x4 hh[2][2] = {}, hl[2][2] = {}, lh[2][2] = {};

    auto issueLoads = [&](int c) {
        const int buf = c & 3;
        char* dA = smem + buf*16384 + tid*16;
        char* dB = smem + buf*16384 + 8192 + tid*16;
        glds16(aSrcH + c*32, dA);
        glds16(aSrcL + c*32, dA + 4096);
        glds16(bSrcH + (size_t)(c*5)*2048, dB);
        glds16(bSrcL + (size_t)(c*5)*2048, dB + 4096);
    };
    auto compute = [&](int c) {
        const char* At = smem + (c & 3)*16384;
        const char* Bt = smem + (c & 3)*16384 + 8192;
        f16x8 ah[2], al[2], bh[2], bl[2];
#pragma unroll
        for (int R = 0; R < 2; ++R) {
            ah[R] = *(const f16x8*)(At + offA[R]);
            al[R] = *(const f16x8*)(At + 4096 + offA[R]);
            bh[R] = *(const f16x8*)(Bt + offB[R]);
            bl[R] = *(const f16x8*)(Bt + 4096 + offB[R]);
        }
#pragma unroll
        for (int R = 0; R < 2; ++R)
#pragma unroll
            for (int C = 0; C < 2; ++C) {
                hh[R][C] = MFMA16(ah[R], bh[C], hh[R][C]);
                hl[R][C] = MFMA16(ah[R], bl[C], hl[R][C]);
                lh[R][C] = MFMA16(al[R], bh[C], lh[R][C]);
            }
    };

    issueLoads(0); issueLoads(1); issueLoads(2);
#pragma unroll 1
    for (int c = 0; c < 29; ++c) {
        WAIT_BAR(8);
        issueLoads(c+3);
        compute(c);
    }
    WAIT_BAR(8); compute(29);
    WAIT_BAR(4); compute(30);
    WAIT_BAR(0); compute(31);

    // ---- fused epilogue: v = fprev + l2b + proj; out + X-next frame limbs ----
#pragma unroll
    for (int R = 0; R < 2; ++R)
#pragma unroll
        for (int C = 0; C < 2; ++C) {
            f32x4 d = hh[R][C] + (hl[R][C] + lh[R][C]) * LOINV;
            int col = ct*64 + wc*32 + C*16 + (l & 15);
            int rb = r0 + wr*32 + R*16 + ((l >> 4) << 2);
#pragma unroll
            for (int j = 0; j < 4; ++j) {
                int b = rb + j;
                if (col < Fsz) {
                    float v = fprev[(size_t)b*TFs + col] + l2b[col] + d[j];
                    outT[(size_t)b*TFs + col] = v;
                    f16 hi, lo;
                    split16(v, hi, lo);
                    XhN[(size_t)b*SX + col] = hi;
                    XlN[(size_t)b*SX + col] = lo;
                } else if (col < 288) {
                    XhN[(size_t)b*SX + col] = (f16)0.f;
                    XlN[(size_t)b*SX + col] = (f16)0.f;
                }
            }
        }
}

extern "C" void kernel_launch(void* const* d_in, const int* in_sizes, int n_in,
                              void* d_out_v, int out_size, void* d_ws, size_t ws_size,
                              hipStream_t stream) {
    const float* motions = (const float*)d_in[0];
    const float* temb    = (const float*)d_in[1];
    const float* ltw     = (const float*)d_in[2];   // (512,768)
    const float* ltb     = (const float*)d_in[3];
    const float* l1w     = (const float*)d_in[4];   // (512,263)
    const float* l1b     = (const float*)d_in[5];
    const float* wih     = (const float*)d_in[6];   // (4096,1024)
    const float* whh     = (const float*)d_in[7];   // (4096,1024)
    const float* bih     = (const float*)d_in[8];
    const float* bhh     = (const float*)d_in[9];
    const float* l2w     = (const float*)d_in[10];  // (263,1024)
    const float* l2b     = (const float*)d_in[11];
    float* out = (float*)d_out_v;
    char* ws = (char*)d_ws;
    if (ws_size < (size_t)WS_BYTES) return;

    f16*   Wpk    = (f16*)(ws + OFF_WPK);
    float* cSt    = (float*)(ws + OFF_CST);
    float* cgp    = (float*)(ws + OFF_CGP);
    f16*   L2h    = (f16*)(ws + OFF_L2PH);
    f16*   L2l    = (f16*)(ws + OFF_L2PL);
    f16*   XhB[2] = { (f16*)(ws + OFF_XHI0), (f16*)(ws + OFF_XHI1) };
    f16*   XlB[2] = { (f16*)(ws + OFF_XLO0), (f16*)(ws + OFF_XLO1) };
    // precompute aliases (dead before the region's loop user)
    float* WihT  = (float*)(ws + OFF_WPK);
    float* Wcomb = (float*)(ws + OFF_WCOMB);
    float* cgj   = (float*)(ws + OFF_CGJ);
    float* WcT   = (float*)(ws + OFF_WCT);
    float* lin1t = (float*)(ws + OFF_PROJ);
    float* biasG = (float*)(ws + OFF_PROJ + 538624u);
    float* ltwT  = (float*)(ws + OFF_XHI0);
    float* textE = (float*)(ws + OFF_XLO1);

    dim3 blk(256);
    tpose<<<dim3(32,128), blk, 0, stream>>>(wih, WihT, 4096, 1024);
    tpose<<<dim3(24, 16), blk, 0, stream>>>(ltw, ltwT, 512, 768);
    tpose<<<dim3( 9, 16), blk, 0, stream>>>(l1w, lin1t, 512, 263);
    biasg_k<<<1024, blk, 0, stream>>>(bih, bhh, l1b, wih, biasG);
    nn_gemm<<<dim3( 8, 8), blk, 0, stream>>>(temb, ltwT, ltb, textE, 256, 256, 512, 768);
    nn_gemm<<<dim3(64, 9), blk, 0, stream>>>(lin1t, WihT, nullptr, Wcomb, 288, 263, 4096, 512);
    nn_gemm<<<dim3(64, 8), blk, 0, stream>>>(textE, WihT + (size_t)512*4096, biasG, cgj,
                                             256, 256, 4096, 512);
    tpose<<<dim3(128, 9), blk, 0, stream>>>(Wcomb, WcT, 288, 4096);
    pack_w<<<dim3(64, 41), blk, 0, stream>>>(WcT, whh, Wpk);
    permute_cg<<<4096, blk, 0, stream>>>(cgj, cgp);
    pack_lin2<<<dim3(5, 32), blk, 0, stream>>>(l2w, L2h, L2l);
    init_k<<<2336, blk, 0, stream>>>(motions, XhB[0], XlB[0], cSt);

    for (int t = 0; t < Tsz; ++t) {
        f16* Xhc = XhB[t & 1],      *Xlc = XlB[t & 1];
        f16* Xhn = XhB[(t+1) & 1],  *Xln = XlB[(t+1) & 1];
        const float* fprev = (t == 0) ? motions : (out + (size_t)(t-1)*Fsz);
        k1_gates<<<dim3(64, 4), blk, 0, stream>>>(Xhc, Xlc, Wpk, cgp, cSt, Xhn, Xln);
        k3_proj<<<dim3(5, 4), blk, 0, stream>>>(Xhn, Xln, L2h, L2l,
                                                fprev, l2b, out + (size_t)t*Fsz, Xhn, Xln);
    }
}

// Round 12
// 7792.283 us; speedup vs baseline: 14.9430x; 14.9430x over previous
//
#include <hip/hip_runtime.h>
#include <math.h>

typedef _Float16 f16;
typedef __attribute__((ext_vector_type(8))) _Float16 f16x8;
typedef __attribute__((ext_vector_type(4))) float f32x4;

#define Bsz 256
#define Tsz 196
#define Fsz 263
#define TFs (Tsz*Fsz)   // 51548
#define SX  1312        // X row stride (288 frame-pad + 1024 h)
#define KCH 41
#define LOSC 2048.0f
#define LOINV 0.00048828125f

// ---------------- ws layout (BYTE offsets) ----------------
#define OFF_WPK    0u            // packed W [41][64][2][64col][32k] f16 = 21495808 B
#define OFF_CST    21495808u     // c state f32 [256][1024] = 1048576
#define OFF_CGP    22544384u     // constG permuted f32 [256][4096] = 4194304
#define OFF_PROJ   26738688u     // (precompute scratch) 2621440
#define OFF_L2PH   29360128u     // lin2 pack hi [32][5][2048] f16 = 655360
#define OFF_L2PL   30015488u
#define OFF_XHI0   30670848u     // 671744 each
#define OFF_XLO0   31342592u
#define OFF_XHI1   32014336u
#define OFF_XLO1   32686080u
#define OFF_WCOMB  33357824u     // scratch 4718592
#define OFF_CGJ    38076416u     // scratch 4194304
#define OFF_WCT    42270720u     // scratch 4718592
#define WS_BYTES   46989312u

__device__ __forceinline__ void glds16(const void* g, void* l) {
    __builtin_amdgcn_global_load_lds(
        (const __attribute__((address_space(1))) void*)g,
        (__attribute__((address_space(3))) void*)l, 16, 0, 0);
}
__device__ __forceinline__ float sigm(float x) { return 1.f / (1.f + expf(-x)); }
__device__ __forceinline__ void split16(float x, f16& hi, f16& lo) {
    hi = (f16)x;
    lo = (f16)((x - (float)hi) * LOSC);
}
#define MFMA16(a,b,c) __builtin_amdgcn_mfma_f32_16x16x32_f16(a,b,c,0,0,0)
#define WAIT_BAR(N) do { \
    asm volatile("s_waitcnt vmcnt(" #N ")" ::: "memory"); \
    __builtin_amdgcn_s_barrier(); \
    __builtin_amdgcn_sched_barrier(0); \
} while (0)

// ---------------- precompute kernels ----------------
__global__ __launch_bounds__(256) void tpose(const float* __restrict__ src,
                                             float* __restrict__ dst, int M, int N) {
    __shared__ float tile[32][33];
    int bx = blockIdx.x, by = blockIdx.y;
    int tx = threadIdx.x & 31, ty = threadIdx.x >> 5;
#pragma unroll
    for (int i = 0; i < 4; ++i) {
        int row = by*32 + ty*4 + i, col = bx*32 + tx;
        tile[ty*4+i][tx] = (row < M && col < N) ? src[(size_t)row*N + col] : 0.f;
    }
    __syncthreads();
#pragma unroll
    for (int i = 0; i < 4; ++i) {
        int row = bx*32 + ty*4 + i, col = by*32 + tx;
        if (row < N && col < M) dst[(size_t)row*M + col] = tile[tx][ty*4+i];
    }
}

__global__ __launch_bounds__(256) void biasg_k(const float* __restrict__ bih,
                                               const float* __restrict__ bhh,
                                               const float* __restrict__ l1b,
                                               const float* __restrict__ wih,
                                               float* __restrict__ bg) {
    int j = blockIdx.x*4 + (threadIdx.x >> 6);
    int l = threadIdx.x & 63;
    const float* wr = wih + (size_t)j*1024 + l*8;
    const float* lb = l1b + l*8;
    float s = 0.f;
#pragma unroll
    for (int e = 0; e < 8; ++e) s += lb[e] * wr[e];
#pragma unroll
    for (int off = 32; off; off >>= 1) s += __shfl_down(s, off, 64);
    if (l == 0) bg[j] = bih[j] + bhh[j] + s;
}

__global__ __launch_bounds__(256) void nn_gemm(const float* __restrict__ A,
                                               const float* __restrict__ B,
                                               const float* __restrict__ bias,
                                               float* __restrict__ C,
                                               int M, int MA, int N, int K) {
    __shared__ float As[32][33];
    __shared__ float Bs[32][64];
    int tid = threadIdx.x;
    int r0 = blockIdx.y*32, c0 = blockIdx.x*64;
    int tr = tid >> 4, tc = tid & 15;
    float acc[2][4] = {};
    for (int k0 = 0; k0 < K; k0 += 32) {
        int m = tid >> 3, kb = (tid & 7)*4;
        int row = r0 + m;
#pragma unroll
        for (int i = 0; i < 4; ++i)
            As[m][kb+i] = (row < MA) ? A[(size_t)row*K + k0 + kb + i] : 0.f;
#pragma unroll
        for (int i = 0; i < 8; ++i) {
            int fi = i*256 + tid, kk = fi >> 6, cc = fi & 63;
            Bs[kk][cc] = B[(size_t)(k0+kk)*N + c0 + cc];
        }
        __syncthreads();
#pragma unroll
        for (int k = 0; k < 32; ++k) {
            float a0 = As[2*tr][k], a1 = As[2*tr+1][k];
            float b0 = Bs[k][4*tc], b1 = Bs[k][4*tc+1], b2 = Bs[k][4*tc+2], b3 = Bs[k][4*tc+3];
            acc[0][0]+=a0*b0; acc[0][1]+=a0*b1; acc[0][2]+=a0*b2; acc[0][3]+=a0*b3;
            acc[1][0]+=a1*b0; acc[1][1]+=a1*b1; acc[1][2]+=a1*b2; acc[1][3]+=a1*b3;
        }
        __syncthreads();
    }
#pragma unroll
    for (int i = 0; i < 2; ++i) {
        int row = r0 + 2*tr + i;
        if (row < M)
#pragma unroll
            for (int j = 0; j < 4; ++j) {
                int col = c0 + 4*tc + j;
                C[(size_t)row*N + col] = acc[i][j] + (bias ? bias[col] : 0.f);
            }
    }
}

// pack W: [kc][ct=64][limb=2][col=64][kslot=4][8] f16, chunk = 8KB.
__global__ __launch_bounds__(256) void pack_w(const float* __restrict__ WcT,
                                              const float* __restrict__ whh,
                                              f16* __restrict__ W) {
    int tid = threadIdx.x;
    int ct = blockIdx.x, kc = blockIdx.y;   // 64, 41
    int c = tid >> 2, s = tid & 3;
    int g = s ^ ((c >> 1) & 3);
    int p = ct*64 + c;
    int j = (p & 3)*1024 + (p >> 2);
#pragma unroll
    for (int limb = 0; limb < 2; ++limb) {
        size_t ob = ((size_t)(kc*64 + ct))*4096 + limb*2048 + c*32 + s*8;
#pragma unroll
        for (int e = 0; e < 8; ++e) {
            int k = kc*32 + g*8 + e;
            float v = (k < 288) ? WcT[(size_t)j*288 + k]
                                : whh[(size_t)j*1024 + (k - 288)];
            f16 hi, lo;
            split16(v, hi, lo);
            W[ob + e] = limb ? lo : hi;
        }
    }
}

// lin2 pack: chunks [kc 0..31][ct 0..4] of 2048 f16 (64 cols x 32 k), per limb
__global__ __launch_bounds__(256) void pack_lin2(const float* __restrict__ l2w,
                                                 f16* __restrict__ Lh,
                                                 f16* __restrict__ Ll) {
    int q = threadIdx.x;
    int ct = blockIdx.x, kc = blockIdx.y;   // ct<5, kc<32
    int k = kc*32 + (((q&3) ^ ((q>>3)&3)) << 3);
    int f = ct*64 + (q>>2);
    size_t ob = ((size_t)(kc*5 + ct)*256 + q)*8;
#pragma unroll
    for (int e = 0; e < 8; ++e) {
        float v = (f < Fsz) ? l2w[(size_t)f*1024 + k + e] : 0.f;
        split16(v, Lh[ob+e], Ll[ob+e]);
    }
}

__global__ __launch_bounds__(256) void permute_cg(const float* __restrict__ cj,
                                                  float* __restrict__ cp) {
    int idx = blockIdx.x*256 + threadIdx.x;
    int b = idx >> 12, p = idx & 4095;
    cp[idx] = cj[(b << 12) + ((p & 3) << 10) + (p >> 2)];
}

__global__ __launch_bounds__(256) void init_k(const float* __restrict__ motions,
                                              f16* __restrict__ Xh0,
                                              f16* __restrict__ Xl0,
                                              float* __restrict__ cSt) {
    int idx = blockIdx.x*256 + threadIdx.x;
    if (idx < 256*SX) {
        int b = idx / SX, k = idx - b*SX;
        float v = (k < Fsz) ? motions[(size_t)b*TFs + k] : 0.f;
        split16(v, Xh0[idx], Xl0[idx]);
    } else if (idx < 256*SX + 262144) {
        cSt[idx - 256*SX] = 0.f;
    }
}

// ---------------- k1: gates GEMM (A direct-to-reg, B glds) + cell update ----------------
// grid (64 ct, 4 rt) = 256 blocks, 256 thr, tile 64x64, waves 2x2 (wave 32x32).
// 6 vmem/chunk/thread (4 A-reg + 2 B-glds), steady WAIT_BAR(6) -> 2-chunk cover.
// ALL register-array indices are compile-time literals (rule #20).
__global__ __launch_bounds__(256) void k1_gates(
        const f16* __restrict__ Xh, const f16* __restrict__ Xl,
        const f16* __restrict__ Wpk,
        const float* __restrict__ cgp, float* __restrict__ cSt,
        f16* __restrict__ XhN, f16* __restrict__ XlN)
{
    __shared__ __attribute__((aligned(16))) char smem[32768];   // 4 B-bufs x 8KB
    const int tid = threadIdx.x;
    const int ct = blockIdx.x, rt = blockIdx.y;
    const int r0 = rt*64, p0 = ct*64;
    const int l = tid & 63;
    const int wr = (tid >> 7) & 1, wc = (tid >> 6) & 1;

    const f16* bSrc  = Wpk + (size_t)ct*4096 + tid*8;
    const f16* aBaseH = Xh + (size_t)(r0 + wr*32 + (l & 15))*SX + (l >> 4)*8;
    const f16* aBaseL = Xl + (size_t)(r0 + wr*32 + (l & 15))*SX + (l >> 4)*8;

    int offB[2];
#pragma unroll
    for (int C = 0; C < 2; ++C) {
        int colB = wc*32 + C*16 + (l & 15);
        offB[C] = colB*64 + ((((l >> 4) ^ ((colB >> 1) & 3)) & 3)*16);
    }
    f32x4 hh[2][2] = {}, hl[2][2] = {}, lh[2][2] = {};
    f16x8 aH0[2], aL0[2], aH1[2], aL1[2], aH2[2], aL2[2], aH3[2], aL3[2];

#define ISSUE_B(c_) do { \
    char* dB = smem + ((c_) & 3)*8192 + tid*16; \
    glds16(bSrc + (size_t)(c_)*262144, dB); \
    glds16(bSrc + (size_t)(c_)*262144 + 2048, dB + 4096); } while(0)
#define ISSUE_A(c_, s_) do { \
    const f16* pH = aBaseH + (c_)*32; const f16* pL = aBaseL + (c_)*32; \
    aH##s_[0] = *(const f16x8*)pH; aH##s_[1] = *(const f16x8*)(pH + 16*SX); \
    aL##s_[0] = *(const f16x8*)pL; aL##s_[1] = *(const f16x8*)(pL + 16*SX); } while(0)
#define COMPUTE(c_, s_) do { \
    const char* Bt = smem + ((c_) & 3)*8192; \
    f16x8 bh0 = *(const f16x8*)(Bt + offB[0]); \
    f16x8 bh1 = *(const f16x8*)(Bt + offB[1]); \
    f16x8 bl0 = *(const f16x8*)(Bt + 4096 + offB[0]); \
    f16x8 bl1 = *(const f16x8*)(Bt + 4096 + offB[1]); \
    hh[0][0] = MFMA16(aH##s_[0], bh0, hh[0][0]); \
    hh[0][1] = MFMA16(aH##s_[0], bh1, hh[0][1]); \
    hh[1][0] = MFMA16(aH##s_[1], bh0, hh[1][0]); \
    hh[1][1] = MFMA16(aH##s_[1], bh1, hh[1][1]); \
    hl[0][0] = MFMA16(aH##s_[0], bl0, hl[0][0]); \
    hl[0][1] = MFMA16(aH##s_[0], bl1, hl[0][1]); \
    hl[1][0] = MFMA16(aH##s_[1], bl0, hl[1][0]); \
    hl[1][1] = MFMA16(aH##s_[1], bl1, hl[1][1]); \
    lh[0][0] = MFMA16(aL##s_[0], bh0, lh[0][0]); \
    lh[0][1] = MFMA16(aL##s_[0], bh1, lh[0][1]); \
    lh[1][0] = MFMA16(aL##s_[1], bh0, lh[1][0]); \
    lh[1][1] = MFMA16(aL##s_[1], bh1, lh[1][1]); } while(0)
#define STEP(c_, sa_, issA_, sc_) do { \
    WAIT_BAR(6); \
    ISSUE_A((issA_), sa_); \
    __builtin_amdgcn_sched_barrier(0); \
    ISSUE_B((c_) + 2); \
    __builtin_amdgcn_sched_barrier(0); \
    COMPUTE(c_, sc_); } while(0)

    // prologue order: A0, A1, B0, A2, B1  (16 ops; first WAIT(6) completes A0,A1,B0)
    ISSUE_A(0, 0);
    __builtin_amdgcn_sched_barrier(0);
    ISSUE_A(1, 1);
    __builtin_amdgcn_sched_barrier(0);
    ISSUE_B(0);
    __builtin_amdgcn_sched_barrier(0);
    ISSUE_A(2, 2);
    __builtin_amdgcn_sched_barrier(0);
    ISSUE_B(1);
    __builtin_amdgcn_sched_barrier(0);

#pragma unroll 1
    for (int cb = 0; cb < 9; ++cb) {
        int c = cb*4;                 // chunks c..c+3, slots 0..3 (literal)
        STEP(c,   3, c+3, 0);
        STEP(c+1, 0, c+4, 1);
        STEP(c+2, 1, c+5, 2);
        STEP(c+3, 2, c+6, 3);
    }
    STEP(36, 3, 39, 0);
    STEP(37, 0, 40, 1);
    WAIT_BAR(6);
    ISSUE_B(40);
    __builtin_amdgcn_sched_barrier(0);
    COMPUTE(38, 2);
    WAIT_BAR(2); COMPUTE(39, 3);
    WAIT_BAR(0); COMPUTE(40, 0);
    __syncthreads();

    // ---- gates -> LDS (swizzled) ----
    float* gl = (float*)smem;   // 64x64 f32 = 16KB
#pragma unroll
    for (int R = 0; R < 2; ++R)
#pragma unroll
        for (int C = 0; C < 2; ++C) {
            f32x4 d = hh[R][C] + (hl[R][C] + lh[R][C]) * LOINV;
            int col = wc*32 + C*16 + (l & 15);
            int rb = wr*32 + R*16 + ((l >> 4) << 2);
#pragma unroll
            for (int j = 0; j < 4; ++j) {
                int r = rb + j;
                gl[r*64 + (col ^ ((r & 7) << 2))] = d[j];
            }
        }
    __syncthreads();
#pragma unroll
    for (int q = 0; q < 4; ++q) {
        int s = q*256 + tid;
        int m = s >> 4, u = s & 15;
        f32x4 gt = *(const f32x4*)(gl + m*64 + ((u << 2) ^ ((m & 7) << 2)));
        f32x4 cg4 = *(const f32x4*)(cgp + (size_t)(r0 + m)*4096 + p0 + (u << 2));
        float gi = gt.x + cg4.x, gf = gt.y + cg4.y, gg = gt.z + cg4.z, go = gt.w + cg4.w;
        int ug = ct*16 + u;
        int ci = (r0 + m)*1024 + ug;
        float cO = cSt[ci];
        float cN = sigm(gf)*cO + sigm(gi)*tanhf(gg);
        float hN = sigm(go)*tanhf(cN);
        cSt[ci] = cN;
        split16(hN, XhN[(size_t)(r0 + m)*SX + 288 + ug],
                    XlN[(size_t)(r0 + m)*SX + 288 + ug]);
    }
#undef ISSUE_B
#undef ISSUE_A
#undef COMPUTE
#undef STEP
}

// ---------------- k3: out-projection full-K + fused frame update ----------------
// grid (5 ct, 4 rt) = 20 blocks, tile 64x64, K=1024 (32 chunks). Epilogue writes
// out[:,t,:] and the frame part of X-next (f16 limbs), pads zeroed.
__global__ __launch_bounds__(256) void k3_proj(
        const f16* __restrict__ Xh, const f16* __restrict__ Xl,  // next-buf (holds h_t)
        const f16* __restrict__ Lh, const f16* __restrict__ Ll,
        const float* __restrict__ fprev, const float* __restrict__ l2b,
        float* __restrict__ outT,
        f16* __restrict__ XhN, f16* __restrict__ XlN)
{
    __shared__ __attribute__((aligned(16))) char smem[65536];   // 4 bufs x 16KB
    const int tid = threadIdx.x;
    const int ct = blockIdx.x, rt = blockIdx.y;
    const int r0 = rt*64;
    const int l = tid & 63;
    const int wr = (tid >> 7) & 1, wc = (tid >> 6) & 1;

    const int aswz = (((tid&3) ^ ((tid>>3)&3)) << 3);
    const f16* aSrcH = Xh + (size_t)(r0 + (tid>>2))*SX + 288 + aswz;
    const f16* aSrcL = Xl + (size_t)(r0 + (tid>>2))*SX + 288 + aswz;
    const f16* bSrcH = Lh + (size_t)ct*2048 + tid*8;
    const f16* bSrcL = Ll + (size_t)ct*2048 + tid*8;

    int offA[2], offB[2];
#pragma unroll
    for (int R = 0; R < 2; ++R) {
        int g = l >> 4;
        int row = wr*32 + R*16 + (l & 15);
        offA[R] = row*64 + ((g ^ ((row>>1)&3)) & 3)*16;
        int col = wc*32 + R*16 + (l & 15);
        offB[R] = col*64 + ((g ^ ((col>>1)&3)) & 3)*16;
    }
    f32x4 hh[2][2] = {}, hl[2][2] = {}, lh[2][2] = {};

    auto issueLoads = [&](int c) {
        const int buf = c & 3;
        char* dA = smem + buf*16384 + tid*16;
        char* dB = smem + buf*16384 + 8192 + tid*16;
        glds16(aSrcH + c*32, dA);
        glds16(aSrcL + c*32, dA + 4096);
        glds16(bSrcH + (size_t)(c*5)*2048, dB);
        glds16(bSrcL + (size_t)(c*5)*2048, dB + 4096);
    };
    auto compute = [&](int c) {
        const char* At = smem + (c & 3)*16384;
        const char* Bt = smem + (c & 3)*16384 + 8192;
        f16x8 ah[2], al[2], bh[2], bl[2];
#pragma unroll
        for (int R = 0; R < 2; ++R) {
            ah[R] = *(const f16x8*)(At + offA[R]);
            al[R] = *(const f16x8*)(At + 4096 + offA[R]);
            bh[R] = *(const f16x8*)(Bt + offB[R]);
            bl[R] = *(const f16x8*)(Bt + 4096 + offB[R]);
        }
#pragma unroll
        for (int R = 0; R < 2; ++R)
#pragma unroll
            for (int C = 0; C < 2; ++C) {
                hh[R][C] = MFMA16(ah[R], bh[C], hh[R][C]);
                hl[R][C] = MFMA16(ah[R], bl[C], hl[R][C]);
                lh[R][C] = MFMA16(al[R], bh[C], lh[R][C]);
            }
    };

    issueLoads(0); issueLoads(1); issueLoads(2);
#pragma unroll 1
    for (int c = 0; c < 29; ++c) {
        WAIT_BAR(8);
        issueLoads(c+3);
        compute(c);
    }
    WAIT_BAR(8); compute(29);
    WAIT_BAR(4); compute(30);
    WAIT_BAR(0); compute(31);

    // ---- fused epilogue: v = fprev + l2b + proj; out + X-next frame limbs ----
#pragma unroll
    for (int R = 0; R < 2; ++R)
#pragma unroll
        for (int C = 0; C < 2; ++C) {
            f32x4 d = hh[R][C] + (hl[R][C] + lh[R][C]) * LOINV;
            int col = ct*64 + wc*32 + C*16 + (l & 15);
            int rb = r0 + wr*32 + R*16 + ((l >> 4) << 2);
#pragma unroll
            for (int j = 0; j < 4; ++j) {
                int b = rb + j;
                if (col < Fsz) {
                    float v = fprev[(size_t)b*TFs + col] + l2b[col] + d[j];
                    outT[(size_t)b*TFs + col] = v;
                    f16 hi, lo;
                    split16(v, hi, lo);
                    XhN[(size_t)b*SX + col] = hi;
                    XlN[(size_t)b*SX + col] = lo;
                } else if (col < 288) {
                    XhN[(size_t)b*SX + col] = (f16)0.f;
                    XlN[(size_t)b*SX + col] = (f16)0.f;
                }
            }
        }
}

extern "C" void kernel_launch(void* const* d_in, const int* in_sizes, int n_in,
                              void* d_out_v, int out_size, void* d_ws, size_t ws_size,
                              hipStream_t stream) {
    const float* motions = (const float*)d_in[0];
    const float* temb    = (const float*)d_in[1];
    const float* ltw     = (const float*)d_in[2];   // (512,768)
    const float* ltb     = (const float*)d_in[3];
    const float* l1w     = (const float*)d_in[4];   // (512,263)
    const float* l1b     = (const float*)d_in[5];
    const float* wih     = (const float*)d_in[6];   // (4096,1024)
    const float* whh     = (const float*)d_in[7];   // (4096,1024)
    const float* bih     = (const float*)d_in[8];
    const float* bhh     = (const float*)d_in[9];
    const float* l2w     = (const float*)d_in[10];  // (263,1024)
    const float* l2b     = (const float*)d_in[11];
    float* out = (float*)d_out_v;
    char* ws = (char*)d_ws;
    if (ws_size < (size_t)WS_BYTES) return;

    f16*   Wpk    = (f16*)(ws + OFF_WPK);
    float* cSt    = (float*)(ws + OFF_CST);
    float* cgp    = (float*)(ws + OFF_CGP);
    f16*   L2h    = (f16*)(ws + OFF_L2PH);
    f16*   L2l    = (f16*)(ws + OFF_L2PL);
    f16*   XhB[2] = { (f16*)(ws + OFF_XHI0), (f16*)(ws + OFF_XHI1) };
    f16*   XlB[2] = { (f16*)(ws + OFF_XLO0), (f16*)(ws + OFF_XLO1) };
    // precompute aliases (dead before the region's loop user)
    float* WihT  = (float*)(ws + OFF_WPK);
    float* Wcomb = (float*)(ws + OFF_WCOMB);
    float* cgj   = (float*)(ws + OFF_CGJ);
    float* WcT   = (float*)(ws + OFF_WCT);
    float* lin1t = (float*)(ws + OFF_PROJ);
    float* biasG = (float*)(ws + OFF_PROJ + 538624u);
    float* ltwT  = (float*)(ws + OFF_XHI0);
    float* textE = (float*)(ws + OFF_XLO1);

    dim3 blk(256);
    tpose<<<dim3(32,128), blk, 0, stream>>>(wih, WihT, 4096, 1024);
    tpose<<<dim3(24, 16), blk, 0, stream>>>(ltw, ltwT, 512, 768);
    tpose<<<dim3( 9, 16), blk, 0, stream>>>(l1w, lin1t, 512, 263);
    biasg_k<<<1024, blk, 0, stream>>>(bih, bhh, l1b, wih, biasG);
    nn_gemm<<<dim3( 8, 8), blk, 0, stream>>>(temb, ltwT, ltb, textE, 256, 256, 512, 768);
    nn_gemm<<<dim3(64, 9), blk, 0, stream>>>(lin1t, WihT, nullptr, Wcomb, 288, 263, 4096, 512);
    nn_gemm<<<dim3(64, 8), blk, 0, stream>>>(textE, WihT + (size_t)512*4096, biasG, cgj,
                                             256, 256, 4096, 512);
    tpose<<<dim3(128, 9), blk, 0, stream>>>(Wcomb, WcT, 288, 4096);
    pack_w<<<dim3(64, 41), blk, 0, stream>>>(WcT, whh, Wpk);
    permute_cg<<<4096, blk, 0, stream>>>(cgj, cgp);
    pack_lin2<<<dim3(5, 32), blk, 0, stream>>>(l2w, L2h, L2l);
    init_k<<<2336, blk, 0, stream>>>(motions, XhB[0], XlB[0], cSt);

    for (int t = 0; t < Tsz; ++t) {
        f16* Xhc = XhB[t & 1],      *Xlc = XlB[t & 1];
        f16* Xhn = XhB[(t+1) & 1],  *Xln = XlB[(t+1) & 1];
        const float* fprev = (t == 0) ? motions : (out + (size_t)(t-1)*Fsz);
        k1_gates<<<dim3(64, 4), blk, 0, stream>>>(Xhc, Xlc, Wpk, cgp, cSt, Xhn, Xln);
        k3_proj<<<dim3(5, 4), blk, 0, stream>>>(Xhn, Xln, L2h, L2l,
                                                fprev, l2b, out + (size_t)t*Fsz, Xhn, Xln);
    }
}

// Round 13
// 6789.005 us; speedup vs baseline: 17.1512x; 1.1478x over previous
//
#include <hip/hip_runtime.h>
#include <math.h>

typedef _Float16 f16;
typedef __attribute__((ext_vector_type(8))) _Float16 f16x8;
typedef __attribute__((ext_vector_type(4))) float f32x4;

#define Bsz 256
#define Tsz 196
#define Fsz 263
#define TFs (Tsz*Fsz)   // 51548
#define SX  1312        // X row stride (288 frame-pad + 1024 h)
#define KCH 41          // 1312/32 k-chunks
#define LOSC 2048.0f
#define LOINV 0.00048828125f

// ---------------- ws layout (BYTE offsets) ----------------
#define OFF_WALLHI 0u            // packed f16 weights hi: 41*64*4096 B
#define OFF_WALLLO 10747904u     // lo (x2048)
// phase-1 alias: WihT fp32 (16.8MB) lives at 0, freed before pack_wall
#define OFF_R1     21495808u     // Wcomb fp32 (pre) -> cSt fp32 (loop)
#define OFF_R2     26214400u     // cgj (pre, 4MB) -> X bufs + proj (loop)
#define OFF_XHI0   26214400u
#define OFF_XLO0   26886144u
#define OFF_XHI1   27557888u
#define OFF_XLO1   28229632u
#define OFF_PROJ   28901376u     // [4 ks][256][320] f32 = 1310720 B
#define OFF_CGP    30408704u     // constG permuted fp32 [256][4096] = 4MB
#define OFF_L2PH   34603008u     // lin2 packed hi: 32*5*4096 B
#define OFF_L2PL   35258368u
#define OFF_LIN1T  35913728u
#define OFF_LTWT   36452352u
#define OFF_TEXTE  38025216u
#define OFF_BIASG  38549504u
#define OFF_WCT    38565888u     // WcombT fp32 [4096][288] = 4718592 B
#define OFF_CTR    43284480u     // 20 u32 per-tile counters
#define WS_BYTES   43284560u

// ---------------- helpers ----------------
__device__ __forceinline__ void glds16(const void* g, void* l) {
    __builtin_amdgcn_global_load_lds(
        (const __attribute__((address_space(1))) void*)g,
        (__attribute__((address_space(3))) void*)l, 16, 0, 0);
}
__device__ __forceinline__ float sigm(float x) { return 1.f / (1.f + expf(-x)); }
__device__ __forceinline__ void split16(float x, f16& hi, f16& lo) {
    hi = (f16)x;
    lo = (f16)((x - (float)hi) * LOSC);
}
#define MFMA16(a,b,c) __builtin_amdgcn_mfma_f32_16x16x32_f16(a,b,c,0,0,0)
#define WAIT_BAR(N) do { \
    asm volatile("s_waitcnt vmcnt(" #N ")" ::: "memory"); \
    __builtin_amdgcn_s_barrier(); \
    __builtin_amdgcn_sched_barrier(0); \
} while (0)

// ---------------- precompute kernels ----------------
__global__ __launch_bounds__(256) void tpose(const float* __restrict__ src,
                                             float* __restrict__ dst, int M, int N) {
    __shared__ float tile[32][33];
    int bx = blockIdx.x, by = blockIdx.y;
    int tx = threadIdx.x & 31, ty = threadIdx.x >> 5;
#pragma unroll
    for (int i = 0; i < 4; ++i) {
        int row = by*32 + ty*4 + i, col = bx*32 + tx;
        tile[ty*4+i][tx] = (row < M && col < N) ? src[(size_t)row*N + col] : 0.f;
    }
    __syncthreads();
#pragma unroll
    for (int i = 0; i < 4; ++i) {
        int row = bx*32 + ty*4 + i, col = by*32 + tx;
        if (row < N && col < M) dst[(size_t)row*M + col] = tile[tx][ty*4+i];
    }
}

__global__ __launch_bounds__(256) void biasg_k(const float* __restrict__ bih,
                                               const float* __restrict__ bhh,
                                               const float* __restrict__ l1b,
                                               const float* __restrict__ wih,
                                               float* __restrict__ bg) {
    int j = blockIdx.x*4 + (threadIdx.x >> 6);
    int l = threadIdx.x & 63;
    const float* wr = wih + (size_t)j*1024 + l*8;
    const float* lb = l1b + l*8;
    float s = 0.f;
#pragma unroll
    for (int e = 0; e < 8; ++e) s += lb[e] * wr[e];
#pragma unroll
    for (int off = 32; off; off >>= 1) s += __shfl_down(s, off, 64);
    if (l == 0) bg[j] = bih[j] + bhh[j] + s;
}

__global__ __launch_bounds__(256) void nn_gemm(const float* __restrict__ A,
                                               const float* __restrict__ B,
                                               const float* __restrict__ bias,
                                               float* __restrict__ C,
                                               int M, int MA, int N, int K) {
    __shared__ float As[32][33];
    __shared__ float Bs[32][64];
    int tid = threadIdx.x;
    int r0 = blockIdx.y*32, c0 = blockIdx.x*64;
    int tr = tid >> 4, tc = tid & 15;
    float acc[2][4] = {};
    for (int k0 = 0; k0 < K; k0 += 32) {
        int m = tid >> 3, kb = (tid & 7)*4;
        int row = r0 + m;
#pragma unroll
        for (int i = 0; i < 4; ++i)
            As[m][kb+i] = (row < MA) ? A[(size_t)row*K + k0 + kb + i] : 0.f;
#pragma unroll
        for (int i = 0; i < 8; ++i) {
            int fi = i*256 + tid, kk = fi >> 6, cc = fi & 63;
            Bs[kk][cc] = B[(size_t)(k0+kk)*N + c0 + cc];
        }
        __syncthreads();
#pragma unroll
        for (int k = 0; k < 32; ++k) {
            float a0 = As[2*tr][k], a1 = As[2*tr+1][k];
            float b0 = Bs[k][4*tc], b1 = Bs[k][4*tc+1], b2 = Bs[k][4*tc+2], b3 = Bs[k][4*tc+3];
            acc[0][0]+=a0*b0; acc[0][1]+=a0*b1; acc[0][2]+=a0*b2; acc[0][3]+=a0*b3;
            acc[1][0]+=a1*b0; acc[1][1]+=a1*b1; acc[1][2]+=a1*b2; acc[1][3]+=a1*b3;
        }
        __syncthreads();
    }
#pragma unroll
    for (int i = 0; i < 2; ++i) {
        int row = r0 + 2*tr + i;
        if (row < M)
#pragma unroll
            for (int j = 0; j < 4; ++j) {
                int col = c0 + 4*tc + j;
                C[(size_t)row*N + col] = acc[i][j] + (bias ? bias[col] : 0.f);
            }
    }
}

// ---------------- pack Wall (hi/lo f16, glds-linear, swizzled) ----------------
__global__ __launch_bounds__(256) void pack_wall(const float* __restrict__ WcT,
                                                 const float* __restrict__ whh,
                                                 f16* __restrict__ Wh,
                                                 f16* __restrict__ Wl) {
    int q = threadIdx.x;
    int ct = blockIdx.x, kc = blockIdx.y;
    int k = kc*32 + (((q&3) ^ ((q>>3)&3)) << 3);
    int p = ct*64 + (q>>2);
    int j = (p&3)*1024 + (p>>2);
    size_t ob = ((size_t)(kc*64 + ct)*256 + q)*8;
#pragma unroll
    for (int e = 0; e < 8; ++e) {
        int kk = k + e;
        float v = (kk < 288) ? WcT[(size_t)j*288 + kk]
                             : whh[(size_t)j*1024 + (kk - 288)];
        split16(v, Wh[ob+e], Wl[ob+e]);
    }
}

__global__ __launch_bounds__(256) void pack_lin2(const float* __restrict__ l2w,
                                                 f16* __restrict__ Lh,
                                                 f16* __restrict__ Ll) {
    int q = threadIdx.x;
    int ct = blockIdx.x, kc = blockIdx.y;   // ct<5, kc<32
    int k = kc*32 + (((q&3) ^ ((q>>3)&3)) << 3);
    int f = ct*64 + (q>>2);
    size_t ob = ((size_t)(kc*5 + ct)*256 + q)*8;
#pragma unroll
    for (int e = 0; e < 8; ++e) {
        float v = (f < Fsz) ? l2w[(size_t)f*1024 + k + e] : 0.f;
        split16(v, Lh[ob+e], Ll[ob+e]);
    }
}

__global__ __launch_bounds__(256) void permute_cg(const float* __restrict__ cj,
                                                  float* __restrict__ cp) {
    int idx = blockIdx.x*256 + threadIdx.x;
    int b = idx >> 12, p = idx & 4095;
    cp[idx] = cj[(b << 12) + ((p & 3) << 10) + (p >> 2)];
}

__global__ __launch_bounds__(256) void init_k(const float* __restrict__ motions,
                                              f16* __restrict__ Xh0,
                                              f16* __restrict__ Xl0,
                                              float* __restrict__ cSt,
                                              unsigned* __restrict__ ctr) {
    int idx = blockIdx.x*256 + threadIdx.x;
    if (idx < 256*SX) {
        int b = idx / SX, k = idx - b*SX;
        float v = (k < Fsz) ? motions[(size_t)b*TFs + k] : 0.f;
        split16(v, Xh0[idx], Xl0[idx]);
    } else if (idx < 256*SX + 262144) {
        cSt[idx - 256*SX] = 0.f;
    } else if (idx < 256*SX + 262144 + 20) {
        ctr[idx - 256*SX - 262144] = 0u;
    }
}

// ---------------- k1: gates GEMM (f16-split MFMA) + cell update (round-6) ----------------
// grid (64 ct, 4 rt), 256 thr = 4 waves, block tile 64 rows x 64 p-cols.
// 4 LDS buffers, depth-3 prefetch, counted vmcnt + raw s_barrier.
__global__ __launch_bounds__(256) void k1_gates(
        const f16* __restrict__ Xh, const f16* __restrict__ Xl,
        const f16* __restrict__ Wh, const f16* __restrict__ Wl,
        const float* __restrict__ cgp, float* __restrict__ cSt,
        f16* __restrict__ XhN, f16* __restrict__ XlN)
{
    __shared__ __attribute__((aligned(16))) char smem[65536];
    const int tid = threadIdx.x;
    const int ct = blockIdx.x, rt = blockIdx.y;
    const int r0 = rt*64, p0 = ct*64;
    const int l = tid & 63;
    const int wr = (tid >> 7) & 1, wc = (tid >> 6) & 1;

    const int aswz = (((tid&3) ^ ((tid>>3)&3)) << 3);
    const f16* aSrcH = Xh + (size_t)(r0 + (tid>>2))*SX + aswz;
    const f16* aSrcL = Xl + (size_t)(r0 + (tid>>2))*SX + aswz;
    const f16* bSrcH = Wh + (size_t)ct*2048 + tid*8;
    const f16* bSrcL = Wl + (size_t)ct*2048 + tid*8;

    int offA[2], offB[2];
#pragma unroll
    for (int R = 0; R < 2; ++R) {
        int g = l >> 4;
        int row = wr*32 + R*16 + (l & 15);
        offA[R] = row*64 + ((g ^ ((row>>1)&3)) & 3)*16;
        int col = wc*32 + R*16 + (l & 15);
        offB[R] = col*64 + ((g ^ ((col>>1)&3)) & 3)*16;
    }
    f32x4 hh[2][2] = {}, hl[2][2] = {}, lh[2][2] = {};

    auto issueLoads = [&](int c) {
        const int buf = c & 3;
        char* dA = smem + buf*8192 + tid*16;
        char* dB = smem + 32768 + buf*8192 + tid*16;
        glds16(aSrcH + c*32, dA);
        glds16(aSrcL + c*32, dA + 4096);
        glds16(bSrcH + (size_t)c*131072, dB);
        glds16(bSrcL + (size_t)c*131072, dB + 4096);
    };
    auto compute = [&](int c) {
        const char* At = smem + (c & 3)*8192;
        const char* Bt = smem + 32768 + (c & 3)*8192;
        f16x8 ah[2], al[2], bh[2], bl[2];
#pragma unroll
        for (int R = 0; R < 2; ++R) {
            ah[R] = *(const f16x8*)(At + offA[R]);
            al[R] = *(const f16x8*)(At + 4096 + offA[R]);
            bh[R] = *(const f16x8*)(Bt + offB[R]);
            bl[R] = *(const f16x8*)(Bt + 4096 + offB[R]);
        }
#pragma unroll
        for (int R = 0; R < 2; ++R)
#pragma unroll
            for (int C = 0; C < 2; ++C) {
                hh[R][C] = MFMA16(ah[R], bh[C], hh[R][C]);
                hl[R][C] = MFMA16(ah[R], bl[C], hl[R][C]);
                lh[R][C] = MFMA16(al[R], bh[C], lh[R][C]);
            }
    };

    issueLoads(0); issueLoads(1); issueLoads(2);
#pragma unroll 1
    for (int c = 0; c < KCH-3; ++c) {
        WAIT_BAR(8);
        issueLoads(c+3);
        compute(c);
    }
    WAIT_BAR(8); compute(KCH-3);
    WAIT_BAR(4); compute(KCH-2);
    WAIT_BAR(0); compute(KCH-1);
    __syncthreads();

    // ---- D -> LDS (swizzled), then fused cell update ----
    float* gl = (float*)smem;   // 64x64 f32 = 16KB
#pragma unroll
    for (int R = 0; R < 2; ++R)
#pragma unroll
        for (int C = 0; C < 2; ++C) {
            f32x4 d = hh[R][C] + (hl[R][C] + lh[R][C]) * LOINV;
            int col = wc*32 + C*16 + (l & 15);
            int rb = wr*32 + R*16 + ((l >> 4) << 2);
#pragma unroll
            for (int j = 0; j < 4; ++j) {
                int r = rb + j;
                gl[r*64 + (col ^ ((r & 7) << 2))] = d[j];
            }
        }
    __syncthreads();
#pragma unroll
    for (int q = 0; q < 4; ++q) {
        int s = q*256 + tid;
        int m = s >> 4, u = s & 15;
        f32x4 gt = *(const f32x4*)(gl + m*64 + ((u << 2) ^ ((m & 7) << 2)));
        f32x4 cg = *(const f32x4*)(cgp + (size_t)(r0 + m)*4096 + p0 + (u << 2));
        float gi = gt.x + cg.x, gf = gt.y + cg.y, gg = gt.z + cg.z, go = gt.w + cg.w;
        int ug = ct*16 + u;
        int ci = (r0 + m)*1024 + ug;
        float cO = cSt[ci];
        float cN = sigm(gf)*cO + sigm(gi)*tanhf(gg);
        float hN = sigm(go)*tanhf(cN);
        cSt[ci] = cN;
        split16(hN, XhN[(size_t)(r0 + m)*SX + 288 + ug], XlN[(size_t)(r0 + m)*SX + 288 + ug]);
    }
}

// ---------------- k3: out-projection split-K x4 + last-finisher tile reduce ----------------
// grid (5 ct, 4 rt, 4 ks) = 80 blocks. Each computes a 64x64 f32 partial (8 chunks).
// Per (ct,rt) tile: agent-scope counter; the 4th arriving block reduces the 4 partials
// in fixed ks order (deterministic), adds fprev+l2b, writes out[:,t,:] + X-next frame
// limbs + pads. First 3 blocks exit (no spin -> deadlock-free).
__global__ __launch_bounds__(256) void k3_proj(
        const f16* __restrict__ Xh, const f16* __restrict__ Xl,  // next-buf (holds h_t)
        const f16* __restrict__ Lh, const f16* __restrict__ Ll,
        float* __restrict__ proj,
        const float* __restrict__ fprev, const float* __restrict__ l2b,
        float* __restrict__ outT,
        f16* __restrict__ XhN, f16* __restrict__ XlN,
        unsigned* __restrict__ ctr)
{
    __shared__ __attribute__((aligned(16))) char smem[65536];
    __shared__ unsigned lastFlag;
    const int tid = threadIdx.x;
    const int ct = blockIdx.x, rt = blockIdx.y, ks = blockIdx.z;
    const int r0 = rt*64;
    const int l = tid & 63;
    const int wr = (tid >> 7) & 1, wc = (tid >> 6) & 1;

    const int aswz = (((tid&3) ^ ((tid>>3)&3)) << 3);
    const f16* aSrcH = Xh + (size_t)(r0 + (tid>>2))*SX + 288 + aswz + ks*256;
    const f16* aSrcL = Xl + (size_t)(r0 + (tid>>2))*SX + 288 + aswz + ks*256;
    const f16* bSrcH = Lh + (size_t)(ks*8)*10240 + (size_t)ct*2048 + tid*8;
    const f16* bSrcL = Ll + (size_t)(ks*8)*10240 + (size_t)ct*2048 + tid*8;

    int offA[2], offB[2];
#pragma unroll
    for (int R = 0; R < 2; ++R) {
        int g = l >> 4;
        int row = wr*32 + R*16 + (l & 15);
        offA[R] = row*64 + ((g ^ ((row>>1)&3)) & 3)*16;
        int col = wc*32 + R*16 + (l & 15);
        offB[R] = col*64 + ((g ^ ((col>>1)&3)) & 3)*16;
    }
    f32x4 hh[2][2] = {}, hl[2][2] = {}, lh[2][2] = {};

    auto issueLoads = [&](int c) {
        const int buf = c & 3;
        char* dA = smem + buf*16384 + tid*16;
        char* dB = smem + buf*16384 + 8192 + tid*16;
        glds16(aSrcH + c*32, dA);
        glds16(aSrcL + c*32, dA + 4096);
        glds16(bSrcH + (size_t)c*10240, dB);
        glds16(bSrcL + (size_t)c*10240, dB + 4096);
    };
    auto compute = [&](int c) {
        const char* At = smem + (c & 3)*16384;
        const char* Bt = smem + (c & 3)*16384 + 8192;
        f16x8 ah[2], al[2], bh[2], bl[2];
#pragma unroll
        for (int R = 0; R < 2; ++R) {
            ah[R] = *(const f16x8*)(At + offA[R]);
            al[R] = *(const f16x8*)(At + 4096 + offA[R]);
            bh[R] = *(const f16x8*)(Bt + offB[R]);
            bl[R] = *(const f16x8*)(Bt + 4096 + offB[R]);
        }
#pragma unroll
        for (int R = 0; R < 2; ++R)
#pragma unroll
            for (int C = 0; C < 2; ++C) {
                hh[R][C] = MFMA16(ah[R], bh[C], hh[R][C]);
                hl[R][C] = MFMA16(ah[R], bl[C], hl[R][C]);
                lh[R][C] = MFMA16(al[R], bh[C], lh[R][C]);
            }
    };

    issueLoads(0); issueLoads(1); issueLoads(2);
#pragma unroll 1
    for (int c = 0; c < 5; ++c) {
        WAIT_BAR(8);
        issueLoads(c+3);
        compute(c);
    }
    WAIT_BAR(8); compute(5);
    WAIT_BAR(4); compute(6);
    WAIT_BAR(0); compute(7);

    float* pout = proj + (size_t)ks*81920;
#pragma unroll
    for (int R = 0; R < 2; ++R)
#pragma unroll
        for (int C = 0; C < 2; ++C) {
            f32x4 d = hh[R][C] + (hl[R][C] + lh[R][C]) * LOINV;
            int col = ct*64 + wc*32 + C*16 + (l & 15);
            int rb = r0 + wr*32 + R*16 + ((l >> 4) << 2);
#pragma unroll
            for (int j = 0; j < 4; ++j)
                pout[(size_t)(rb + j)*320 + col] = d[j];
        }

    // ---- last-finisher reduce (no spinning) ----
    __syncthreads();   // each wave drains vmcnt(0) before barrier -> stores complete
    if (tid == 0) {
        __builtin_amdgcn_fence(__ATOMIC_RELEASE, "agent");
        unsigned old = __hip_atomic_fetch_add(&ctr[rt*5 + ct], 1u,
                                              __ATOMIC_ACQ_REL, __HIP_MEMORY_SCOPE_AGENT);
        lastFlag = old;
        if (old == 3u)
            __hip_atomic_store(&ctr[rt*5 + ct], 0u, __ATOMIC_RELAXED,
                               __HIP_MEMORY_SCOPE_AGENT);
    }
    __syncthreads();
    if (lastFlag != 3u) return;
    __builtin_amdgcn_fence(__ATOMIC_ACQUIRE, "agent");

#pragma unroll 1
    for (int idx = tid; idx < 4096; idx += 256) {
        int r = idx >> 6, cc = idx & 63;
        int b = r0 + r;
        int f = ct*64 + cc;
        if (f < 288) {
            size_t xo = (size_t)b*SX + f;
            if (f < Fsz) {
                size_t po = (size_t)b*320 + f;
                float s = proj[po] + proj[81920 + po] + proj[163840 + po] + proj[245760 + po];
                float v = fprev[(size_t)b*TFs + f] + l2b[f] + s;
                outT[(size_t)b*TFs + f] = v;
                f16 hi, lo;
                split16(v, hi, lo);
                XhN[xo] = hi;
                XlN[xo] = lo;
            } else {
                XhN[xo] = (f16)0.f;
                XlN[xo] = (f16)0.f;
            }
        }
    }
}

extern "C" void kernel_launch(void* const* d_in, const int* in_sizes, int n_in,
                              void* d_out_v, int out_size, void* d_ws, size_t ws_size,
                              hipStream_t stream) {
    const float* motions = (const float*)d_in[0];
    const float* temb    = (const float*)d_in[1];
    const float* ltw     = (const float*)d_in[2];   // (512,768)
    const float* ltb     = (const float*)d_in[3];
    const float* l1w     = (const float*)d_in[4];   // (512,263)
    const float* l1b     = (const float*)d_in[5];
    const float* wih     = (const float*)d_in[6];   // (4096,1024)
    const float* whh     = (const float*)d_in[7];   // (4096,1024)
    const float* bih     = (const float*)d_in[8];
    const float* bhh     = (const float*)d_in[9];
    const float* l2w     = (const float*)d_in[10];  // (263,1024)
    const float* l2b     = (const float*)d_in[11];
    float* out = (float*)d_out_v;
    char* ws = (char*)d_ws;
    if (ws_size < (size_t)WS_BYTES) return;

    f16*      WallHi = (f16*)(ws + OFF_WALLHI);
    f16*      WallLo = (f16*)(ws + OFF_WALLLO);
    float*    cSt    = (float*)(ws + OFF_R1);
    f16*      XhB[2] = { (f16*)(ws + OFF_XHI0), (f16*)(ws + OFF_XHI1) };
    f16*      XlB[2] = { (f16*)(ws + OFF_XLO0), (f16*)(ws + OFF_XLO1) };
    float*    proj   = (float*)(ws + OFF_PROJ);
    float*    cgp    = (float*)(ws + OFF_CGP);
    f16*      L2h    = (f16*)(ws + OFF_L2PH);
    f16*      L2l    = (f16*)(ws + OFF_L2PL);
    unsigned* ctr    = (unsigned*)(ws + OFF_CTR);
    // precompute aliases (dead before their region's loop user)
    float* WihT  = (float*)(ws + OFF_WALLHI);
    float* Wcomb = (float*)(ws + OFF_R1);
    float* cgj   = (float*)(ws + OFF_R2);
    float* lin1t = (float*)(ws + OFF_LIN1T);
    float* ltwT  = (float*)(ws + OFF_LTWT);
    float* textE = (float*)(ws + OFF_TEXTE);
    float* biasG = (float*)(ws + OFF_BIASG);
    float* WcT   = (float*)(ws + OFF_WCT);

    dim3 blk(256);
    // ---- precompute ----
    tpose<<<dim3(32,128), blk, 0, stream>>>(wih, WihT, 4096, 1024);
    tpose<<<dim3(24, 16), blk, 0, stream>>>(ltw, ltwT, 512, 768);
    tpose<<<dim3( 9, 16), blk, 0, stream>>>(l1w, lin1t, 512, 263);
    biasg_k<<<1024, blk, 0, stream>>>(bih, bhh, l1b, wih, biasG);
    nn_gemm<<<dim3( 8, 8), blk, 0, stream>>>(temb, ltwT, ltb, textE, 256, 256, 512, 768);
    nn_gemm<<<dim3(64, 9), blk, 0, stream>>>(lin1t, WihT, nullptr, Wcomb, 288, 263, 4096, 512);
    nn_gemm<<<dim3(64, 8), blk, 0, stream>>>(textE, WihT + (size_t)512*4096, biasG, cgj,
                                             256, 256, 4096, 512);
    tpose<<<dim3(128, 9), blk, 0, stream>>>(Wcomb, WcT, 288, 4096);
    permute_cg<<<4096, blk, 0, stream>>>(cgj, cgp);
    pack_wall<<<dim3(64, 41), blk, 0, stream>>>(WcT, whh, WallHi, WallLo);
    pack_lin2<<<dim3(5, 32), blk, 0, stream>>>(l2w, L2h, L2l);
    init_k<<<2337, blk, 0, stream>>>(motions, XhB[0], XlB[0], cSt, ctr);

    // ---- recurrence: 2 kernels/step ----
    for (int t = 0; t < Tsz; ++t) {
        f16* Xhc = XhB[t & 1],      *Xlc = XlB[t & 1];
        f16* Xhn = XhB[(t+1) & 1],  *Xln = XlB[(t+1) & 1];
        const float* fprev = (t == 0) ? motions : (out + (size_t)(t-1)*Fsz);
        k1_gates<<<dim3(64, 4), blk, 0, stream>>>(Xhc, Xlc, WallHi, WallLo,
                                                  cgp, cSt, Xhn, Xln);
        k3_proj<<<dim3(5, 4, 4), blk, 0, stream>>>(Xhn, Xln, L2h, L2l, proj,
                                                   fprev, l2b, out + (size_t)t*Fsz,
                                                   Xhn, Xln, ctr);
    }
}

// Round 14
// 5087.210 us; speedup vs baseline: 22.8887x; 1.3345x over previous
//
#include <hip/hip_runtime.h>
#include <math.h>

typedef _Float16 f16;
typedef __attribute__((ext_vector_type(8))) _Float16 f16x8;
typedef __attribute__((ext_vector_type(4))) float f32x4;

#define Bsz 256
#define Tsz 196
#define Fsz 263
#define TFs (Tsz*Fsz)   // 51548
#define SX  1312        // X row stride (288 frame-pad + 1024 h)
#define KCH 41          // 1312/32 k-chunks
#define LOSC 2048.0f
#define LOINV 0.00048828125f

// ---------------- ws layout (BYTE offsets) ----------------
#define OFF_WALLHI 0u            // packed f16 weights hi: 41*64*4096 B
#define OFF_WALLLO 10747904u     // lo (x2048)
// phase-1 alias: WihT fp32 (16.8MB) lives at 0, freed before pack_wall
#define OFF_R1     21495808u     // Wcomb fp32 (pre) -> cSt fp32 (loop)
#define OFF_R2     26214400u     // cgj (pre, 4MB) -> X bufs (loop)
#define OFF_XHI0   26214400u
#define OFF_XLO0   26886144u
#define OFF_XHI1   27557888u
#define OFF_XLO1   28229632u
#define OFF_CGP    30408704u     // constG permuted fp32 [256][4096] = 4MB
#define OFF_LPK    34603008u     // lin2 pack [32 kc][9 fct][256 slot][8] f16 = 1179648 B
#define OFF_LIN1T  35913728u
#define OFF_LTWT   36452352u
#define OFF_TEXTE  38025216u
#define OFF_BIASG  38549504u
#define OFF_WCT    38565888u     // WcombT fp32 [4096][288] = 4718592 B
#define WS_BYTES   43284480u

// ---------------- helpers ----------------
__device__ __forceinline__ void glds16(const void* g, void* l) {
    __builtin_amdgcn_global_load_lds(
        (const __attribute__((address_space(1))) void*)g,
        (__attribute__((address_space(3))) void*)l, 16, 0, 0);
}
__device__ __forceinline__ float sigm(float x) { return 1.f / (1.f + expf(-x)); }
__device__ __forceinline__ void split16(float x, f16& hi, f16& lo) {
    hi = (f16)x;
    lo = (f16)((x - (float)hi) * LOSC);
}
#define MFMA16(a,b,c) __builtin_amdgcn_mfma_f32_16x16x32_f16(a,b,c,0,0,0)
#define WAIT_BAR(N) do { \
    asm volatile("s_waitcnt vmcnt(" #N ")" ::: "memory"); \
    __builtin_amdgcn_s_barrier(); \
    __builtin_amdgcn_sched_barrier(0); \
} while (0)

// ---------------- precompute kernels ----------------
__global__ __launch_bounds__(256) void tpose(const float* __restrict__ src,
                                             float* __restrict__ dst, int M, int N) {
    __shared__ float tile[32][33];
    int bx = blockIdx.x, by = blockIdx.y;
    int tx = threadIdx.x & 31, ty = threadIdx.x >> 5;
#pragma unroll
    for (int i = 0; i < 4; ++i) {
        int row = by*32 + ty*4 + i, col = bx*32 + tx;
        tile[ty*4+i][tx] = (row < M && col < N) ? src[(size_t)row*N + col] : 0.f;
    }
    __syncthreads();
#pragma unroll
    for (int i = 0; i < 4; ++i) {
        int row = bx*32 + ty*4 + i, col = by*32 + tx;
        if (row < N && col < M) dst[(size_t)row*M + col] = tile[tx][ty*4+i];
    }
}

__global__ __launch_bounds__(256) void biasg_k(const float* __restrict__ bih,
                                               const float* __restrict__ bhh,
                                               const float* __restrict__ l1b,
                                               const float* __restrict__ wih,
                                               float* __restrict__ bg) {
    int j = blockIdx.x*4 + (threadIdx.x >> 6);
    int l = threadIdx.x & 63;
    const float* wr = wih + (size_t)j*1024 + l*8;
    const float* lb = l1b + l*8;
    float s = 0.f;
#pragma unroll
    for (int e = 0; e < 8; ++e) s += lb[e] * wr[e];
#pragma unroll
    for (int off = 32; off; off >>= 1) s += __shfl_down(s, off, 64);
    if (l == 0) bg[j] = bih[j] + bhh[j] + s;
}

__global__ __launch_bounds__(256) void nn_gemm(const float* __restrict__ A,
                                               const float* __restrict__ B,
                                               const float* __restrict__ bias,
                                               float* __restrict__ C,
                                               int M, int MA, int N, int K) {
    __shared__ float As[32][33];
    __shared__ float Bs[32][64];
    int tid = threadIdx.x;
    int r0 = blockIdx.y*32, c0 = blockIdx.x*64;
    int tr = tid >> 4, tc = tid & 15;
    float acc[2][4] = {};
    for (int k0 = 0; k0 < K; k0 += 32) {
        int m = tid >> 3, kb = (tid & 7)*4;
        int row = r0 + m;
#pragma unroll
        for (int i = 0; i < 4; ++i)
            As[m][kb+i] = (row < MA) ? A[(size_t)row*K + k0 + kb + i] : 0.f;
#pragma unroll
        for (int i = 0; i < 8; ++i) {
            int fi = i*256 + tid, kk = fi >> 6, cc = fi & 63;
            Bs[kk][cc] = B[(size_t)(k0+kk)*N + c0 + cc];
        }
        __syncthreads();
#pragma unroll
        for (int k = 0; k < 32; ++k) {
            float a0 = As[2*tr][k], a1 = As[2*tr+1][k];
            float b0 = Bs[k][4*tc], b1 = Bs[k][4*tc+1], b2 = Bs[k][4*tc+2], b3 = Bs[k][4*tc+3];
            acc[0][0]+=a0*b0; acc[0][1]+=a0*b1; acc[0][2]+=a0*b2; acc[0][3]+=a0*b3;
            acc[1][0]+=a1*b0; acc[1][1]+=a1*b1; acc[1][2]+=a1*b2; acc[1][3]+=a1*b3;
        }
        __syncthreads();
    }
#pragma unroll
    for (int i = 0; i < 2; ++i) {
        int row = r0 + 2*tr + i;
        if (row < M)
#pragma unroll
            for (int j = 0; j < 4; ++j) {
                int col = c0 + 4*tc + j;
                C[(size_t)row*N + col] = acc[i][j] + (bias ? bias[col] : 0.f);
            }
    }
}

// ---------------- pack Wall (hi/lo f16, glds-linear, swizzled) ----------------
__global__ __launch_bounds__(256) void pack_wall(const float* __restrict__ WcT,
                                                 const float* __restrict__ whh,
                                                 f16* __restrict__ Wh,
                                                 f16* __restrict__ Wl) {
    int q = threadIdx.x;
    int ct = blockIdx.x, kc = blockIdx.y;
    int k = kc*32 + (((q&3) ^ ((q>>3)&3)) << 3);
    int p = ct*64 + (q>>2);
    int j = (p&3)*1024 + (p>>2);
    size_t ob = ((size_t)(kc*64 + ct)*256 + q)*8;
#pragma unroll
    for (int e = 0; e < 8; ++e) {
        int kk = k + e;
        float v = (kk < 288) ? WcT[(size_t)j*288 + kk]
                             : whh[(size_t)j*1024 + (kk - 288)];
        split16(v, Wh[ob+e], Wl[ob+e]);
    }
}

// ---------------- pack lin2 for k3b: [kc][fct=9][256 slot][8] f16 ----------------
// slot q: limb = q>>7, s = q&127, col = s>>2, g = (s&3) ^ ((col>>1)&3)
__global__ __launch_bounds__(256) void pack_lp32(const float* __restrict__ l2w,
                                                 f16* __restrict__ Lpk) {
    int fct = blockIdx.x, kc = blockIdx.y;   // 9, 32
    int q = threadIdx.x;
    int limb = q >> 7, s = q & 127;
    int col = s >> 2;
    int g = (s & 3) ^ ((col >> 1) & 3);
    int f = fct*32 + col;
    size_t ob = ((size_t)(kc*9 + fct)*256 + q)*8;
#pragma unroll
    for (int e = 0; e < 8; ++e) {
        float v = (f < Fsz) ? l2w[(size_t)f*1024 + kc*32 + g*8 + e] : 0.f;
        f16 hi, lo;
        split16(v, hi, lo);
        Lpk[ob + e] = limb ? lo : hi;
    }
}

__global__ __launch_bounds__(256) void permute_cg(const float* __restrict__ cj,
                                                  float* __restrict__ cp) {
    int idx = blockIdx.x*256 + threadIdx.x;
    int b = idx >> 12, p = idx & 4095;
    cp[idx] = cj[(b << 12) + ((p & 3) << 10) + (p >> 2)];
}

__global__ __launch_bounds__(256) void init_k(const float* __restrict__ motions,
                                              f16* __restrict__ Xh0,
                                              f16* __restrict__ Xl0,
                                              float* __restrict__ cSt) {
    int idx = blockIdx.x*256 + threadIdx.x;
    if (idx < 256*SX) {
        int b = idx / SX, k = idx - b*SX;
        float v = (k < Fsz) ? motions[(size_t)b*TFs + k] : 0.f;
        split16(v, Xh0[idx], Xl0[idx]);
    } else if (idx < 256*SX + 262144) {
        cSt[idx - 256*SX] = 0.f;
    }
}

// ---------------- k1: gates GEMM (f16-split MFMA) + cell update (round-6 verbatim) ----------------
__global__ __launch_bounds__(256) void k1_gates(
        const f16* __restrict__ Xh, const f16* __restrict__ Xl,
        const f16* __restrict__ Wh, const f16* __restrict__ Wl,
        const float* __restrict__ cgp, float* __restrict__ cSt,
        f16* __restrict__ XhN, f16* __restrict__ XlN)
{
    __shared__ __attribute__((aligned(16))) char smem[65536];
    const int tid = threadIdx.x;
    const int ct = blockIdx.x, rt = blockIdx.y;
    const int r0 = rt*64, p0 = ct*64;
    const int l = tid & 63;
    const int wr = (tid >> 7) & 1, wc = (tid >> 6) & 1;

    const int aswz = (((tid&3) ^ ((tid>>3)&3)) << 3);
    const f16* aSrcH = Xh + (size_t)(r0 + (tid>>2))*SX + aswz;
    const f16* aSrcL = Xl + (size_t)(r0 + (tid>>2))*SX + aswz;
    const f16* bSrcH = Wh + (size_t)ct*2048 + tid*8;
    const f16* bSrcL = Wl + (size_t)ct*2048 + tid*8;

    int offA[2], offB[2];
#pragma unroll
    for (int R = 0; R < 2; ++R) {
        int g = l >> 4;
        int row = wr*32 + R*16 + (l & 15);
        offA[R] = row*64 + ((g ^ ((row>>1)&3)) & 3)*16;
        int col = wc*32 + R*16 + (l & 15);
        offB[R] = col*64 + ((g ^ ((col>>1)&3)) & 3)*16;
    }
    f32x4 hh[2][2] = {}, hl[2][2] = {}, lh[2][2] = {};

    auto issueLoads = [&](int c) {
        const int buf = c & 3;
        char* dA = smem + buf*8192 + tid*16;
        char* dB = smem + 32768 + buf*8192 + tid*16;
        glds16(aSrcH + c*32, dA);
        glds16(aSrcL + c*32, dA + 4096);
        glds16(bSrcH + (size_t)c*131072, dB);
        glds16(bSrcL + (size_t)c*131072, dB + 4096);
    };
    auto compute = [&](int c) {
        const char* At = smem + (c & 3)*8192;
        const char* Bt = smem + 32768 + (c & 3)*8192;
        f16x8 ah[2], al[2], bh[2], bl[2];
#pragma unroll
        for (int R = 0; R < 2; ++R) {
            ah[R] = *(const f16x8*)(At + offA[R]);
            al[R] = *(const f16x8*)(At + 4096 + offA[R]);
            bh[R] = *(const f16x8*)(Bt + offB[R]);
            bl[R] = *(const f16x8*)(Bt + 4096 + offB[R]);
        }
#pragma unroll
        for (int R = 0; R < 2; ++R)
#pragma unroll
            for (int C = 0; C < 2; ++C) {
                hh[R][C] = MFMA16(ah[R], bh[C], hh[R][C]);
                hl[R][C] = MFMA16(ah[R], bl[C], hl[R][C]);
                lh[R][C] = MFMA16(al[R], bh[C], lh[R][C]);
            }
    };

    issueLoads(0); issueLoads(1); issueLoads(2);
#pragma unroll 1
    for (int c = 0; c < KCH-3; ++c) {
        WAIT_BAR(8);
        issueLoads(c+3);
        compute(c);
    }
    WAIT_BAR(8); compute(KCH-3);
    WAIT_BAR(4); compute(KCH-2);
    WAIT_BAR(0); compute(KCH-1);
    __syncthreads();

    // ---- D -> LDS (swizzled), then fused cell update ----
    float* gl = (float*)smem;   // 64x64 f32 = 16KB
#pragma unroll
    for (int R = 0; R < 2; ++R)
#pragma unroll
        for (int C = 0; C < 2; ++C) {
            f32x4 d = hh[R][C] + (hl[R][C] + lh[R][C]) * LOINV;
            int col = wc*32 + C*16 + (l & 15);
            int rb = wr*32 + R*16 + ((l >> 4) << 2);
#pragma unroll
            for (int j = 0; j < 4; ++j) {
                int r = rb + j;
                gl[r*64 + (col ^ ((r & 7) << 2))] = d[j];
            }
        }
    __syncthreads();
#pragma unroll
    for (int q = 0; q < 4; ++q) {
        int s = q*256 + tid;
        int m = s >> 4, u = s & 15;
        f32x4 gt = *(const f32x4*)(gl + m*64 + ((u << 2) ^ ((m & 7) << 2)));
        f32x4 cg = *(const f32x4*)(cgp + (size_t)(r0 + m)*4096 + p0 + (u << 2));
        float gi = gt.x + cg.x, gf = gt.y + cg.y, gg = gt.z + cg.z, go = gt.w + cg.w;
        int ug = ct*16 + u;
        int ci = (r0 + m)*1024 + ug;
        float cO = cSt[ci];
        float cN = sigm(gf)*cO + sigm(gi)*tanhf(gg);
        float hN = sigm(go)*tanhf(cN);
        cSt[ci] = cN;
        split16(hN, XhN[(size_t)(r0 + m)*SX + 288 + ug], XlN[(size_t)(r0 + m)*SX + 288 + ug]);
    }
}

// ---------------- k3b: out-projection + in-block split-K reduce + fused epilogue ----------------
// grid (9 fct, 8 rt2) = 72 blocks x 1024 thr (16 waves = 4 k-groups x 4 waves).
// Tile 32 rows x 32 f-cols; each group handles K-slice kg*256..+256 (8 chunks of 32).
// Block-local sync only (no fences): partials -> LDS -> __syncthreads -> reduce ->
// out[:,t,:] + X-next frame limbs + pads.
__global__ __launch_bounds__(1024) void k3b(
        const f16* __restrict__ Xh, const f16* __restrict__ Xl,   // next-buf (holds h_t)
        const f16* __restrict__ Lpk,
        const float* __restrict__ fprev, const float* __restrict__ l2b,
        float* __restrict__ outT,
        f16* __restrict__ XhN, f16* __restrict__ XlN)
{
    __shared__ __attribute__((aligned(16))) char smem[65536];   // 4 grp x 2 buf x 8KB
    const int tid = threadIdx.x;
    const int fct = blockIdx.x, rt2 = blockIdx.y;
    const int kg = tid >> 8, q2 = tid & 255;
    const int wv = (tid >> 6) & 3, wr = wv >> 1, wc = wv & 1;
    const int l = tid & 63;

    // staging source (per thread: 1 A-slot + 1 B-slot, 16B each)
    const int limb = q2 >> 7, slot = q2 & 127;
    const int arow = slot >> 2;
    const int ag = (slot & 3) ^ ((arow >> 1) & 3);
    const f16* aSrc = (limb ? Xl : Xh) + (size_t)(rt2*32 + arow)*SX + 288 + kg*256 + ag*8;
    char* const myBuf0 = smem + kg*16384;

    // frag read offsets (within a buf: A at 0 [hi],2048 [lo]; B at 4096,6144)
    const int rowA = wr*16 + (l & 15);
    const int aoff = (rowA*4 + (((l >> 4) ^ ((rowA >> 1) & 3)) & 3))*16;
    const int colB = wc*16 + (l & 15);
    const int boff = 4096 + (colB*4 + (((l >> 4) ^ ((colB >> 1) & 3)) & 3))*16;

    f32x4 hh = {}, hl = {}, lh = {};

    auto stage = [&](int c) {
        char* buf = myBuf0 + (c & 1)*8192;
        glds16(aSrc + c*32, buf + q2*16);
        glds16(Lpk + ((size_t)((kg*8 + c)*9 + fct)*256 + q2)*8, buf + 4096 + q2*16);
    };
    auto compute = [&](int c) {
        const char* buf = myBuf0 + (c & 1)*8192;
        f16x8 ah = *(const f16x8*)(buf + aoff);
        f16x8 al = *(const f16x8*)(buf + 2048 + aoff);
        f16x8 bh = *(const f16x8*)(buf + boff);
        f16x8 bl = *(const f16x8*)(buf + 2048 + boff);
        hh = MFMA16(ah, bh, hh);
        hl = MFMA16(ah, bl, hl);
        lh = MFMA16(al, bh, lh);
    };

    stage(0);
#pragma unroll 1
    for (int c = 0; c < 8; ++c) {
        asm volatile("s_waitcnt vmcnt(0)" ::: "memory");
        __builtin_amdgcn_s_barrier();
        __builtin_amdgcn_sched_barrier(0);
        if (c < 7) stage(c+1);          // writes buf (c+1)&1; its last reader
        __builtin_amdgcn_sched_barrier(0); // (compute c-1) finished before barrier
        compute(c);                      // reads buf c&1
    }
    __syncthreads();                     // all groups done before redBuf overlay

    // ---- partials -> LDS (overlay [0,16KB)) ----
    float* red = (float*)smem;
    {
        f32x4 d = hh + (hl + lh) * LOINV;
        int rb = wr*16 + ((l >> 4) << 2);
#pragma unroll
        for (int j = 0; j < 4; ++j) {
            int r = rb + j;
            red[kg*1024 + r*32 + (colB ^ ((r & 7) << 2))] = d[j];
        }
    }
    __syncthreads();

    // ---- reduce + epilogue: one elem per thread (32x32) ----
    {
        int r = (tid >> 5) & 31, cc = tid & 31;
        int sw = cc ^ ((r & 7) << 2);
        float s = red[r*32 + sw] + red[1024 + r*32 + sw]
                + red[2048 + r*32 + sw] + red[3072 + r*32 + sw];
        int f = fct*32 + cc;
        int b = rt2*32 + r;
        size_t xo = (size_t)b*SX + f;
        if (f < Fsz) {
            float v = fprev[(size_t)b*TFs + f] + l2b[f] + s;
            outT[(size_t)b*TFs + f] = v;
            f16 hi, lo;
            split16(v, hi, lo);
            XhN[xo] = hi;
            XlN[xo] = lo;
        } else {                         // f in [263,288): zero pads
            XhN[xo] = (f16)0.f;
            XlN[xo] = (f16)0.f;
        }
    }
}

extern "C" void kernel_launch(void* const* d_in, const int* in_sizes, int n_in,
                              void* d_out_v, int out_size, void* d_ws, size_t ws_size,
                              hipStream_t stream) {
    const float* motions = (const float*)d_in[0];
    const float* temb    = (const float*)d_in[1];
    const float* ltw     = (const float*)d_in[2];   // (512,768)
    const float* ltb     = (const float*)d_in[3];
    const float* l1w     = (const float*)d_in[4];   // (512,263)
    const float* l1b     = (const float*)d_in[5];
    const float* wih     = (const float*)d_in[6];   // (4096,1024)
    const float* whh     = (const float*)d_in[7];   // (4096,1024)
    const float* bih     = (const float*)d_in[8];
    const float* bhh     = (const float*)d_in[9];
    const float* l2w     = (const float*)d_in[10];  // (263,1024)
    const float* l2b     = (const float*)d_in[11];
    float* out = (float*)d_out_v;
    char* ws = (char*)d_ws;
    if (ws_size < (size_t)WS_BYTES) return;

    f16*   WallHi = (f16*)(ws + OFF_WALLHI);
    f16*   WallLo = (f16*)(ws + OFF_WALLLO);
    float* cSt    = (float*)(ws + OFF_R1);
    f16*   XhB[2] = { (f16*)(ws + OFF_XHI0), (f16*)(ws + OFF_XHI1) };
    f16*   XlB[2] = { (f16*)(ws + OFF_XLO0), (f16*)(ws + OFF_XLO1) };
    float* cgp    = (float*)(ws + OFF_CGP);
    f16*   Lpk    = (f16*)(ws + OFF_LPK);
    // precompute aliases (dead before their region's loop user)
    float* WihT  = (float*)(ws + OFF_WALLHI);
    float* Wcomb = (float*)(ws + OFF_R1);
    float* cgj   = (float*)(ws + OFF_R2);
    float* lin1t = (float*)(ws + OFF_LIN1T);
    float* ltwT  = (float*)(ws + OFF_LTWT);
    float* textE = (float*)(ws + OFF_TEXTE);
    float* biasG = (float*)(ws + OFF_BIASG);
    float* WcT   = (float*)(ws + OFF_WCT);

    dim3 blk(256);
    // ---- precompute ----
    tpose<<<dim3(32,128), blk, 0, stream>>>(wih, WihT, 4096, 1024);
    tpose<<<dim3(24, 16), blk, 0, stream>>>(ltw, ltwT, 512, 768);
    tpose<<<dim3( 9, 16), blk, 0, stream>>>(l1w, lin1t, 512, 263);
    biasg_k<<<1024, blk, 0, stream>>>(bih, bhh, l1b, wih, biasG);
    nn_gemm<<<dim3( 8, 8), blk, 0, stream>>>(temb, ltwT, ltb, textE, 256, 256, 512, 768);
    nn_gemm<<<dim3(64, 9), blk, 0, stream>>>(lin1t, WihT, nullptr, Wcomb, 288, 263, 4096, 512);
    nn_gemm<<<dim3(64, 8), blk, 0, stream>>>(textE, WihT + (size_t)512*4096, biasG, cgj,
                                             256, 256, 4096, 512);
    tpose<<<dim3(128, 9), blk, 0, stream>>>(Wcomb, WcT, 288, 4096);
    permute_cg<<<4096, blk, 0, stream>>>(cgj, cgp);
    pack_wall<<<dim3(64, 41), blk, 0, stream>>>(WcT, whh, WallHi, WallLo);
    pack_lp32<<<dim3(9, 32), blk, 0, stream>>>(l2w, Lpk);
    init_k<<<2336, blk, 0, stream>>>(motions, XhB[0], XlB[0], cSt);

    // ---- recurrence: 2 kernels/step, no fences ----
    for (int t = 0; t < Tsz; ++t) {
        f16* Xhc = XhB[t & 1],      *Xlc = XlB[t & 1];
        f16* Xhn = XhB[(t+1) & 1],  *Xln = XlB[(t+1) & 1];
        const float* fprev = (t == 0) ? motions : (out + (size_t)(t-1)*Fsz);
        k1_gates<<<dim3(64, 4), blk, 0, stream>>>(Xhc, Xlc, WallHi, WallLo,
                                                  cgp, cSt, Xhn, Xln);
        k3b<<<dim3(9, 8), dim3(1024), 0, stream>>>(Xhn, Xln, Lpk,
                                                   fprev, l2b, out + (size_t)t*Fsz,
                                                   Xhn, Xln);
    }
}